// Round 15
// baseline (1118.389 us; speedup 1.0000x reference)
//
#include <hip/hip_runtime.h>
#include <hip/hip_bf16.h>
#include <stdint.h>

#define NN 50000
#define EE 100000
#define DD 768
#define MP 50176   // 196 * 256
#define KIN 96     // 78 padded to 96
#define SCB 196    // ceil(50000/256) scan blocks

typedef _Float16 half_t;
typedef __attribute__((ext_vector_type(8))) _Float16 v8h;
typedef __attribute__((ext_vector_type(4))) float v4f;

__device__ __forceinline__ void gload16(const half_t* g, half_t* l){
  __builtin_amdgcn_global_load_lds(
      (const __attribute__((address_space(1))) unsigned int*)(g),
      (__attribute__((address_space(3))) unsigned int*)(l),
      16, 0, 0);
}

// ================= 256x256 GEMM, r12 single-barrier pipeline schedule =================
// 512 threads = 8 waves (4M x 2N), wave tile 64x128 (same per-wave shape as proven r12);
// BK=32; 3 LDS buffers (96 KB) -> 1 block/CU, 8 waves = 2/SIMD (same occupancy as r12).
// Per-CU L2-staging traffic 32KB/iter vs r12's 48KB (-33%) — the measured co-limiter.
// vmcnt ledger (4 gloads/stage): at iter top outstanding = stages (i+1),(i+2) = 8;
// need tile i+1 -> vmcnt(4). Prologue: 12 outstanding, tile0 = first 4 -> vmcnt(8).
// Buffer WAR: lgkmcnt(0)+barrier at iter top drains all waves' LOADF(i) reads of buf i%3
// before STAGE(i+3) overwrites it.
// MODE 0: o16 = f16(acc + bias)   (LDS-transpose epilogue)
// MODE 1: o16 = f16(acc)          (LDS-transpose epilogue)
// MODE 2: o32 = acc + bias        (fp32 direct stores, rows < NN)
template<int MODE, int KK>
__global__ __launch_bounds__(512, 1)
void gemm_t(const half_t* __restrict__ A,
            const half_t* __restrict__ Bt,
            const float* __restrict__ bias,
            float* __restrict__ o32,
            half_t* __restrict__ o16)
{
  constexpr int NKT = KK/32;
  __shared__ __align__(16) half_t lds[3*16384];   // 3 bufs x (A 256x32 | B 256x32) = 96 KB

  // bijective XCD swizzle (m204), col-fastest (3 col-blocks share an A-panel)
  const int nwg = gridDim.x;
  const int q = nwg >> 3, r = nwg & 7;
  const int xcd = blockIdx.x & 7, ii = blockIdx.x >> 3;
  const int L = (xcd < r ? xcd*(q+1) : r*(q+1) + (xcd-r)*q) + ii;
  const int rowb = L / 3, colb = L - rowb*3;
  const int m0 = rowb*256, n0 = colb*256;

  const int t = threadIdx.x, l = t&63, w = t>>6;
  const int wm = w>>1, wn = w&1;       // 4M x 2N; wave tile = 64 x 128

  v4f acc[4][8];
  #pragma unroll
  for (int i=0;i<4;++i)
    #pragma unroll
    for (int j=0;j<8;++j){ v4f z = {0.f,0.f,0.f,0.f}; acc[i][j]=z; }

  // staging: instr j covers rows [128j,128j+128); thread t -> row 128j+16w+(l>>2), phys chunk l&3
  // source logical chunk = (l&3) ^ ((row>>1)&3) = (l&3) ^ ((l>>3)&3)   (16w,128j == 0 mod 8)
  const int srow = 16*w + (l>>2);
  const int sch  = ((l&3) ^ ((l>>3)&3))*8;
  const half_t* ApA = A  + (size_t)(m0 + srow)*KK + sch;
  const half_t* ApB = Bt + (size_t)(n0 + srow)*KK + sch;
  const int aoff = w*512;              // wave-uniform LDS base (halfs), + lane*16B by HW

  auto STAGE = [&](int kt2, int b){
    half_t* Ab = lds + b*16384;
    half_t* Bb = Ab + 8192;
    const int ko = kt2*32;
    gload16(ApA + ko,                   Ab + aoff);
    gload16(ApA + ko + (size_t)128*KK,  Ab + aoff + 4096);
    gload16(ApB + ko,                   Bb + aoff);
    gload16(ApB + ko + (size_t)128*KK,  Bb + aoff + 4096);
  };

  // fragment reads: row = base + m*16 + ra (base%8==0); phys chunk = (l>>4) ^ ((ra>>1)&3)
  const int ra = l&15;
  const int pc = ((l>>4) ^ ((ra>>1)&3))*8;

  v8h af[2][4], bf[2][8];

  #define LOADF(s_, base_) do{                                              \
    const half_t* Ab_ = lds + (base_);                                      \
    const half_t* Bb_ = Ab_ + 8192;                                         \
    _Pragma("unroll")                                                       \
    for (int n_=0;n_<8;++n_) bf[s_][n_] = *(const v8h*)(Bb_ + (wn*128 + n_*16 + ra)*32 + pc); \
    _Pragma("unroll")                                                       \
    for (int m_=0;m_<4;++m_) af[s_][m_] = *(const v8h*)(Ab_ + (wm*64 + m_*16 + ra)*32 + pc); \
  }while(0)

  #define MFMAS(s_) do{                                                     \
    __builtin_amdgcn_s_setprio(1);                                          \
    _Pragma("unroll")                                                       \
    for (int m_=0;m_<4;++m_)                                                \
      _Pragma("unroll")                                                     \
      for (int n_=0;n_<8;++n_)                                              \
        acc[m_][n_] = __builtin_amdgcn_mfma_f32_16x16x32_f16(af[s_][m_], bf[s_][n_], acc[m_][n_], 0,0,0); \
    __builtin_amdgcn_s_setprio(0);                                          \
  }while(0)

  // prologue: fill 3 buffers (12 loads), land tile 0 (first 4), read its fragments
  STAGE(0,0); STAGE(1,1); STAGE(2,2);
  asm volatile("s_waitcnt vmcnt(8)" ::: "memory");   // tile 0 landed (this wave)
  __builtin_amdgcn_s_barrier();                      // all waves' tile 0 landed
  asm volatile("" ::: "memory");
  LOADF(0, 0);

  #pragma unroll
  for (int i=0;i<NKT;++i){
    const int cur = i&1, nxt = cur^1;
    if (i < NKT-2) asm volatile("s_waitcnt vmcnt(4) lgkmcnt(0)" ::: "memory");
    else           asm volatile("s_waitcnt vmcnt(0) lgkmcnt(0)" ::: "memory");
    __builtin_amdgcn_s_barrier();
    asm volatile("" ::: "memory");
    if (i+3 < NKT) STAGE(i+3, i%3);                  // overwrite fully-consumed buffer
    if (i+1 < NKT) LOADF(nxt, ((i+1)%3)*16384);      // reg prefetch (overlaps MFMAs)
    MFMAS(cur);
  }
  #undef LOADF
  #undef MFMAS

  if (MODE==2){
    float bv[8];
    #pragma unroll
    for (int n=0;n<8;++n) bv[n] = bias[n0 + wn*128 + n*16 + ra];
    #pragma unroll
    for (int m=0;m<4;++m){
      #pragma unroll
      for (int rr=0;rr<4;++rr){
        int row = m0 + wm*64 + m*16 + (l>>4)*4 + rr;
        if (row >= NN) continue;
        #pragma unroll
        for (int n=0;n<8;++n){
          int col = n0 + wn*128 + n*16 + ra;
          o32[(size_t)row*DD + col] = acc[m][n][rr] + bv[n];
        }
      }
    }
  } else {
    // LDS-transpose epilogue: two 128-row passes (128x256 halfs = 64 KB of the 96 KB)
    // granule-XOR swizzle: 16B granule g of row r stored at g ^ (r&7)  (bijective)
    #pragma unroll
    for (int p=0;p<2;++p){
      __syncthreads();   // all waves done with K-loop LDS reads / previous pass
      if ((wm>>1)==p){
        #pragma unroll
        for (int m=0;m<4;++m){
          #pragma unroll
          for (int rr=0;rr<4;++rr){
            int row = (wm&1)*64 + m*16 + (l>>4)*4 + rr;
            #pragma unroll
            for (int n=0;n<8;++n){
              int col = wn*128 + n*16 + ra;
              float v = acc[m][n][rr];
              if (MODE==0) v += bias[n0+col];
              int gran = (col>>3) ^ (row&7);
              lds[row*256 + gran*8 + (col&7)] = (half_t)v;
            }
          }
        }
      }
      __syncthreads();
      #pragma unroll
      for (int pi=0; pi<8; ++pi){
        int row = pi*16 + (t>>5);
        int g = t&31;
        v8h hv = *(const v8h*)(lds + row*256 + ((g ^ (row&7)))*8);
        *(v8h*)(o16 + (size_t)(m0 + p*128 + row)*DD + n0 + g*8) = hv;   // pad rows harmless
      }
    }
  }
}

// ---------------- degree / CSR build ----------------
__global__ void k_count(const int* __restrict__ dst, int* __restrict__ cnt){
  int e = blockIdx.x*256 + threadIdx.x;
  if (e < EE) atomicAdd(&cnt[dst[e]], 1);
}
__global__ void k_dinv(const int* __restrict__ cnt, float* __restrict__ dinv){
  int i = blockIdx.x*256 + threadIdx.x;
  if (i < MP) dinv[i] = (i < NN) ? rsqrtf((float)cnt[i] + 1.0f) : 0.f;
}
__global__ void k_bsum(const int* __restrict__ cnt, int* __restrict__ bsum){
  int i = blockIdx.x*256 + threadIdx.x;
  int v = (i < NN) ? cnt[i] : 0;
  #pragma unroll
  for (int o=1;o<64;o<<=1) v += __shfl_xor(v, o);
  __shared__ int ws_[4];
  if ((threadIdx.x&63)==0) ws_[threadIdx.x>>6] = v;
  __syncthreads();
  if (threadIdx.x==0) bsum[blockIdx.x] = ws_[0]+ws_[1]+ws_[2]+ws_[3];
}
__global__ void k_btop(const int* __restrict__ bsum, int* __restrict__ boff){
  if (threadIdx.x==0){
    int run = 0;
    for (int b=0;b<SCB;++b){ boff[b] = run; run += bsum[b]; }
  }
}
__global__ void k_rowptr(const int* __restrict__ cnt, const int* __restrict__ boff,
                         int* __restrict__ rowptr, int* __restrict__ cursor){
  __shared__ int sh[256];
  int i = blockIdx.x*256 + threadIdx.x;
  int v = (i < NN) ? cnt[i] : 0;
  sh[threadIdx.x] = v; __syncthreads();
  #pragma unroll
  for (int o=1;o<256;o<<=1){
    int add = 0;
    if (threadIdx.x >= o) add = sh[threadIdx.x - o];
    __syncthreads();
    sh[threadIdx.x] += add;
    __syncthreads();
  }
  int excl = sh[threadIdx.x] - v + boff[blockIdx.x];
  if (i <= NN) rowptr[i] = excl;
  if (i < NN)  cursor[i] = excl;
}
__global__ void k_fill(const int* __restrict__ src, const int* __restrict__ dst,
                       const float* __restrict__ dinv, int* __restrict__ cursor,
                       int* __restrict__ ss, float* __restrict__ we){
  int e = blockIdx.x*256 + threadIdx.x;
  if (e < EE){
    int s = src[e], d = dst[e];
    int pos = atomicAdd(&cursor[d], 1);
    ss[pos] = s;
    we[pos] = dinv[s]*dinv[d];
  }
}
__global__ void k_x16(const float* __restrict__ x, half_t* __restrict__ x16){
  int idx = blockIdx.x*256 + threadIdx.x;
  if (idx < MP*KIN){
    int row = idx / KIN, k = idx - row*KIN;
    float v = (row < NN && k < 78) ? x[(size_t)row*78 + k] : 0.f;
    x16[idx] = (half_t)v;
  }
}

// ---------------- LDS-tiled coalesced transpose: src fp32 [K x 768] -> dst f16 [768 x ldk] ----------------
__global__ __launch_bounds__(256)
void k_trt(const float* __restrict__ src, half_t* __restrict__ dst,
           int K, int ldk, size_t srcStride, size_t dstStride){
  __shared__ half_t sh[32][33];
  const float* s = src + blockIdx.z*srcStride;
  half_t* d = dst + blockIdx.z*dstStride;
  const int tx = threadIdx.x & 31, ty = threadIdx.x >> 5;   // 32 x 8
  const int kb = blockIdx.y*32, nb = blockIdx.x*32;
  #pragma unroll
  for (int rloop=0; rloop<4; ++rloop){
    int krow = kb + ty*4 + rloop;
    float v = (krow < K) ? s[(size_t)krow*DD + nb + tx] : 0.f;
    sh[ty*4+rloop][tx] = (half_t)v;
  }
  __syncthreads();
  #pragma unroll
  for (int rloop=0; rloop<4; ++rloop){
    int nrow = ty*4 + rloop;
    d[(size_t)(nb + nrow)*ldk + kb + tx] = sh[tx][nrow];
  }
}

// ---------------- CSR gather, wave-per-row: 4 waves/block, lane l owns cols l+64j (j=0..11) ----------------
__global__ __launch_bounds__(256)
void k_gather(const int* __restrict__ rowptr, const int* __restrict__ ss,
              const float* __restrict__ we, const half_t* __restrict__ xw,
              const float* __restrict__ dinv, const float* __restrict__ bias,
              half_t* __restrict__ agg16, float* __restrict__ stats){
  const int t = threadIdx.x, l = t&63, wv = t>>6;
  float b_[12];
  #pragma unroll
  for (int j=0;j<12;++j) b_[j] = bias[l + 64*j];
  float s_[12], q_[12];
  #pragma unroll
  for (int j=0;j<12;++j){ s_[j]=0.f; q_[j]=0.f; }

  for (int d = blockIdx.x*4 + wv; d < NN; d += gridDim.x*4){
    int beg = rowptr[d], end = rowptr[d+1];
    float dv = dinv[d], sn = dv*dv;
    const half_t* xr = xw + (size_t)d*DD + l;
    float a_[12];
    #pragma unroll
    for (int j=0;j<12;++j) a_[j] = fmaf(sn, (float)xr[64*j], b_[j]);
    int e = beg;
    for (; e+1 < end; e += 2){
      int sA = ss[e], sB = ss[e+1];
      float wA = we[e], wB = we[e+1];
      const half_t* xA = xw + (size_t)sA*DD + l;
      const half_t* xB = xw + (size_t)sB*DD + l;
      #pragma unroll
      for (int j=0;j<12;++j) a_[j] += wA*(float)xA[64*j] + wB*(float)xB[64*j];
    }
    if (e < end){
      int sA = ss[e]; float wA = we[e];
      const half_t* xA = xw + (size_t)sA*DD + l;
      #pragma unroll
      for (int j=0;j<12;++j) a_[j] = fmaf(wA, (float)xA[64*j], a_[j]);
    }
    half_t* ar = agg16 + (size_t)d*DD + l;
    #pragma unroll
    for (int j=0;j<12;++j) ar[64*j] = (half_t)a_[j];
    #pragma unroll
    for (int j=0;j<12;++j){ s_[j]+=a_[j]; q_[j]+=a_[j]*a_[j]; }
  }

  __shared__ float red[4][24][64];   // 24 KB
  #pragma unroll
  for (int j=0;j<12;++j){ red[wv][j][l] = s_[j]; red[wv][12+j][l] = q_[j]; }
  __syncthreads();
  #pragma unroll
  for (int k=0;k<6;++k){
    int idx  = t + k*256;
    int slot = idx>>6, lane = idx&63;
    float v = red[0][slot][lane]+red[1][slot][lane]+red[2][slot][lane]+red[3][slot][lane];
    int off = (slot<12) ? (lane + 64*slot) : (DD + lane + 64*(slot-12));
    atomicAdd(&stats[off], v);
  }
}

// ---------------- fused BN-finalize + apply: h16 += relu(agg*sc + sh) ----------------
// grid MUST be 1536 blocks x 256 so each thread's column set is loop-invariant
__global__ __launch_bounds__(256)
void k_apply(const half_t* __restrict__ agg16, const float* __restrict__ stats,
             const float* __restrict__ g, const float* __restrict__ b,
             half_t* __restrict__ h16){
  const int tid = blockIdx.x*256 + threadIdx.x;
  const int col = (tid*8) % DD;
  float sc[8], sh[8];
  #pragma unroll
  for (int j=0;j<8;++j){
    float mu  = stats[col+j]    * (1.0f/NN);
    float msq = stats[DD+col+j] * (1.0f/NN);
    float var = msq - mu*mu;
    float rstd = rsqrtf(var + 1e-5f);
    float scale = rstd * g[col+j];
    sc[j] = scale;
    sh[j] = b[col+j] - mu*scale;
  }
  const int total = NN*DD/8;
  for (int i = tid; i < total; i += 1536*256){
    size_t base = (size_t)i*8;
    v8h a = *(const v8h*)(agg16 + base);
    v8h h = *(const v8h*)(h16 + base);
    v8h o;
    #pragma unroll
    for (int j=0;j<8;++j){
      float v = fmaxf(fmaf((float)a[j], sc[j], sh[j]), 0.f);
      o[j] = (half_t)((float)h[j] + v);
    }
    *(v8h*)(h16 + base) = o;
  }
}

extern "C" void kernel_launch(void* const* d_in, const int* in_sizes, int n_in,
                              void* d_out, int out_size, void* d_ws, size_t ws_size,
                              hipStream_t stream){
  (void)in_sizes; (void)n_in; (void)out_size; (void)ws_size;
  const float* x      = (const float*)d_in[0];
  const int*   ei     = (const int*)  d_in[1];
  const float* in_w   = (const float*)d_in[2];
  const float* in_b   = (const float*)d_in[3];
  const float* conv_w = (const float*)d_in[4];
  const float* conv_b = (const float*)d_in[5];
  const float* bn_g   = (const float*)d_in[6];
  const float* bn_b   = (const float*)d_in[7];
  const float* out_w  = (const float*)d_in[8];
  const float* out_b  = (const float*)d_in[9];
  float* out = (float*)d_out;
  const int* srcI = ei;
  const int* dstI = ei + EE;

  char* ws = (char*)d_ws; size_t off = 0;
  auto alloc = [&](size_t b)->void*{ void* p = ws + off; off += (b + 255) & ~(size_t)255; return p; };
  half_t* h16  = (half_t*)alloc((size_t)MP*DD*2);
  half_t* xw16 = (half_t*)alloc((size_t)MP*DD*2);
  half_t* agg16= (half_t*)alloc((size_t)NN*DD*2);
  half_t* x16  = (half_t*)alloc((size_t)MP*KIN*2);
  half_t* wT   = (half_t*)alloc((size_t)(DD*KIN + 6*DD*DD)*2);
  float* dinv   = (float*)alloc((size_t)MP*4);
  int*   cnt    = (int*)  alloc((size_t)MP*4);
  int*   rowptr = (int*)  alloc((size_t)(NN+1)*4);
  int*   cursor = (int*)  alloc((size_t)NN*4);
  int*   ssE    = (int*)  alloc((size_t)EE*4);
  float* weE    = (float*)alloc((size_t)EE*4);
  int*   bsum   = (int*)  alloc((size_t)SCB*4);
  int*   boff   = (int*)  alloc((size_t)SCB*4);
  float* stats5 = (float*)alloc((size_t)5*2*DD*4);   // 5 layers x {sum, sumsq}

  half_t* wTin = wT;
  half_t* wTc  = wT + DD*KIN;
  half_t* wTo  = wTc + 5*DD*DD;

  hipMemsetAsync(cnt, 0, (size_t)MP*4, stream);
  hipMemsetAsync(stats5, 0, (size_t)5*2*DD*4, stream);
  k_count<<<(EE+255)/256,256,0,stream>>>(dstI, cnt);
  k_dinv <<<(MP+255)/256,256,0,stream>>>(cnt, dinv);
  k_bsum <<<SCB,256,0,stream>>>(cnt, bsum);
  k_btop <<<1,64,0,stream>>>(bsum, boff);
  k_rowptr<<<SCB,256,0,stream>>>(cnt, boff, rowptr, cursor);
  k_fill <<<(EE+255)/256,256,0,stream>>>(srcI, dstI, dinv, cursor, ssE, weE);
  k_x16  <<<(MP*KIN+255)/256,256,0,stream>>>(x, x16);
  {
    dim3 gin(DD/32, KIN/32, 1);            // in_w: 78x768 -> 768x96 (pad zeros)
    k_trt<<<gin,256,0,stream>>>(in_w, wTin, 78, KIN, 0, 0);
    dim3 gc(DD/32, DD/32, 5);              // conv_w: 5 x 768x768
    k_trt<<<gc,256,0,stream>>>(conv_w, wTc, DD, DD, (size_t)DD*DD, (size_t)DD*DD);
    dim3 go(DD/32, DD/32, 1);              // out_w
    k_trt<<<go,256,0,stream>>>(out_w, wTo, DD, DD, 0, 0);
  }

  const int NWG = (MP/256)*(DD/256);   // 196*3 = 588
  gemm_t<0,KIN><<<NWG,512,0,stream>>>(x16, wTin, in_b, nullptr, h16);

  for (int l = 0; l < 5; ++l){
    float* statsL = stats5 + (size_t)l*2*DD;
    gemm_t<1,DD><<<NWG,512,0,stream>>>(h16, wTc + (size_t)l*DD*DD, nullptr, nullptr, xw16);
    k_gather<<<2048,256,0,stream>>>(rowptr, ssE, weE, xw16, dinv, conv_b + l*DD, agg16, statsL);
    k_apply<<<1536,256,0,stream>>>(agg16, statsL, bn_g + l*DD, bn_b + l*DD, h16);
  }

  gemm_t<2,DD><<<NWG,512,0,stream>>>(h16, wTo, out_b, out, nullptr);
}

// Round 16
// 1051.956 us; speedup vs baseline: 1.0632x; 1.0632x over previous
//
#include <hip/hip_runtime.h>
#include <hip/hip_bf16.h>
#include <stdint.h>

#define NN 50000
#define EE 100000
#define DD 768
#define MP 50176   // 392 * 128
#define KIN 96     // 78 padded to 96
#define SCB 196    // ceil(50000/256) scan blocks

typedef _Float16 half_t;
typedef __attribute__((ext_vector_type(8))) _Float16 v8h;
typedef __attribute__((ext_vector_type(4))) float v4f;

__device__ __forceinline__ void gload16(const half_t* g, half_t* l){
  __builtin_amdgcn_global_load_lds(
      (const __attribute__((address_space(1))) unsigned int*)(g),
      (__attribute__((address_space(3))) unsigned int*)(l),
      16, 0, 0);
}

// ================= 128x256 GEMM, r12/r14 pipeline schedule (PROVEN 86us), 2 blocks/CU =================
// 256 threads = 4 waves (2M x 2N), wave tile 64x128; BK=32; 3 LDS buffers (72 KB).
// Per iter: ONE combined wait (vmcnt lgkmcnt) + ONE barrier; STAGE(i+3) (6 gloads),
// LOADF(i+1) (12 ds_read_b128, reg prefetch), MFMAS(i) (32 MFMA).
// vmcnt ledger (6 loads/stage): at iter top outstanding = stages (i+1),(i+2) = 12;
// need tile i+1 -> vmcnt(6). Last two iters drain to 0.
// MODE 0: o16 = f16(acc + bias)   (LDS-transpose epilogue)
// MODE 1: o16 = f16(acc)          (LDS-transpose epilogue)
// MODE 2: o32 = acc + bias        (fp32 direct stores, rows < NN)
template<int MODE, int KK>
__global__ __launch_bounds__(256, 2)
void gemm_t(const half_t* __restrict__ A,
            const half_t* __restrict__ Bt,
            const float* __restrict__ bias,
            float* __restrict__ o32,
            half_t* __restrict__ o16)
{
  constexpr int NKT = KK/32;
  __shared__ __align__(16) half_t lds[3*12288];   // 3 bufs x (A 128x32 | B 256x32) = 72 KB

  // bijective XCD swizzle (m204), col-fastest (3 col-blocks share an A-panel)
  const int nwg = gridDim.x;
  const int q = nwg >> 3, r = nwg & 7;
  const int xcd = blockIdx.x & 7, ii = blockIdx.x >> 3;
  const int L = (xcd < r ? xcd*(q+1) : r*(q+1) + (xcd-r)*q) + ii;
  const int rowb = L / 3, colb = L - rowb*3;
  const int m0 = rowb*128, n0 = colb*256;

  const int t = threadIdx.x, l = t&63, w = t>>6;
  const int wm = w>>1, wn = w&1;       // wave tile = 64 x 128

  v4f acc[4][8];
  #pragma unroll
  for (int i=0;i<4;++i)
    #pragma unroll
    for (int j=0;j<8;++j){ v4f z = {0.f,0.f,0.f,0.f}; acc[i][j]=z; }

  // staging: gload j covers rows [64j,64j+64); thread t -> row 64j+16w+(l>>2), phys chunk l&3
  // source logical chunk = (l&3) ^ ((row>>1)&3) = (l&3) ^ ((l>>3)&3)
  const int srow = 16*w + (l>>2);
  const int sch  = ((l&3) ^ ((l>>3)&3))*8;
  const half_t* ApA = A  + (size_t)(m0 + srow)*KK + sch;
  const half_t* ApB = Bt + (size_t)(n0 + srow)*KK + sch;
  const int aoff = w*512;              // wave-uniform LDS base (halfs), + lane*16B by HW

  auto STAGE = [&](int kt2, int b){
    half_t* Ab = lds + b*12288;
    half_t* Bb = Ab + 4096;
    const int ko = kt2*32;
    gload16(ApA + ko,                   Ab + aoff);
    gload16(ApA + ko + (size_t)64*KK,   Ab + aoff + 2048);
    gload16(ApB + ko,                   Bb + aoff);
    gload16(ApB + ko + (size_t)64*KK,   Bb + aoff + 2048);
    gload16(ApB + ko + (size_t)128*KK,  Bb + aoff + 4096);
    gload16(ApB + ko + (size_t)192*KK,  Bb + aoff + 6144);
  };

  // fragment reads: row = base + m*16 + ra (base%8==0); phys chunk = (l>>4) ^ ((ra>>1)&3)
  const int ra = l&15;
  const int pc = ((l>>4) ^ ((ra>>1)&3))*8;

  v8h af[2][4], bf[2][8];

  #define LOADF(s_, base_) do{                                              \
    const half_t* Ab_ = lds + (base_);                                      \
    const half_t* Bb_ = Ab_ + 4096;                                         \
    _Pragma("unroll")                                                       \
    for (int n_=0;n_<8;++n_) bf[s_][n_] = *(const v8h*)(Bb_ + (wn*128 + n_*16 + ra)*32 + pc); \
    _Pragma("unroll")                                                       \
    for (int m_=0;m_<4;++m_) af[s_][m_] = *(const v8h*)(Ab_ + (wm*64 + m_*16 + ra)*32 + pc); \
  }while(0)

  #define MFMAS(s_) do{                                                     \
    __builtin_amdgcn_s_setprio(1);                                          \
    _Pragma("unroll")                                                       \
    for (int m_=0;m_<4;++m_)                                                \
      _Pragma("unroll")                                                     \
      for (int n_=0;n_<8;++n_)                                              \
        acc[m_][n_] = __builtin_amdgcn_mfma_f32_16x16x32_f16(af[s_][m_], bf[s_][n_], acc[m_][n_], 0,0,0); \
    __builtin_amdgcn_s_setprio(0);                                          \
  }while(0)

  // prologue: fill 3 buffers (18 loads), land tile 0 (first 6), read its fragments
  STAGE(0,0); STAGE(1,1); STAGE(2,2);
  asm volatile("s_waitcnt vmcnt(12)" ::: "memory");  // tile 0 landed (this wave)
  __builtin_amdgcn_s_barrier();                      // all waves' tile 0 landed
  asm volatile("" ::: "memory");
  LOADF(0, 0);

  #pragma unroll
  for (int i=0;i<NKT;++i){
    const int cur = i&1, nxt = cur^1;
    if (i < NKT-2) asm volatile("s_waitcnt vmcnt(6) lgkmcnt(0)" ::: "memory");
    else           asm volatile("s_waitcnt vmcnt(0) lgkmcnt(0)" ::: "memory");
    __builtin_amdgcn_s_barrier();
    asm volatile("" ::: "memory");
    if (i+3 < NKT) STAGE(i+3, i%3);                  // overwrite fully-consumed buffer
    if (i+1 < NKT) LOADF(nxt, ((i+1)%3)*12288);      // reg prefetch (overlaps MFMAs)
    MFMAS(cur);
  }
  #undef LOADF
  #undef MFMAS

  if (MODE==2){
    float bv[8];
    #pragma unroll
    for (int n=0;n<8;++n) bv[n] = bias[n0 + wn*128 + n*16 + ra];
    #pragma unroll
    for (int m=0;m<4;++m){
      #pragma unroll
      for (int rr=0;rr<4;++rr){
        int row = m0 + wm*64 + m*16 + (l>>4)*4 + rr;
        if (row >= NN) continue;
        #pragma unroll
        for (int n=0;n<8;++n){
          int col = n0 + wn*128 + n*16 + ra;
          o32[(size_t)row*DD + col] = acc[m][n][rr] + bv[n];
        }
      }
    }
  } else {
    // LDS-transpose epilogue: 128x256 halfs (64 KB of the 72 KB)
    // granule-XOR swizzle: 16B granule g of row r stored at g ^ (r&7)  (bijective)
    __syncthreads();   // all waves done with K-loop LDS reads
    #pragma unroll
    for (int m=0;m<4;++m){
      #pragma unroll
      for (int rr=0;rr<4;++rr){
        int row = wm*64 + m*16 + (l>>4)*4 + rr;
        #pragma unroll
        for (int n=0;n<8;++n){
          int col = wn*128 + n*16 + ra;
          float v = acc[m][n][rr];
          if (MODE==0) v += bias[n0+col];
          int gran = (col>>3) ^ (row&7);
          lds[row*256 + gran*8 + (col&7)] = (half_t)v;
        }
      }
    }
    __syncthreads();
    #pragma unroll
    for (int p=0;p<16;++p){
      int row = p*8 + (t>>5);
      int g = t&31;
      v8h hv = *(const v8h*)(lds + row*256 + ((g ^ (row&7)))*8);
      *(v8h*)(o16 + (size_t)(m0+row)*DD + n0 + g*8) = hv;   // pad rows harmless
    }
  }
}

// ---------------- degree / CSR build ----------------
__global__ void k_count(const int* __restrict__ dst, int* __restrict__ cnt){
  int e = blockIdx.x*256 + threadIdx.x;
  if (e < EE) atomicAdd(&cnt[dst[e]], 1);
}
// fused: dinv[i] = rsqrt(cnt+1)  AND per-block sums of cnt (for the scan)
__global__ void k_dinv_bsum(const int* __restrict__ cnt, float* __restrict__ dinv,
                            int* __restrict__ bsum){
  int i = blockIdx.x*256 + threadIdx.x;
  int c = (i < NN) ? cnt[i] : 0;
  if (i < MP) dinv[i] = (i < NN) ? rsqrtf((float)c + 1.0f) : 0.f;
  int v = c;
  #pragma unroll
  for (int o=1;o<64;o<<=1) v += __shfl_xor(v, o);
  __shared__ int ws_[4];
  if ((threadIdx.x&63)==0) ws_[threadIdx.x>>6] = v;
  __syncthreads();
  if (threadIdx.x==0 && blockIdx.x < SCB) bsum[blockIdx.x] = ws_[0]+ws_[1]+ws_[2]+ws_[3];
}
__global__ void k_btop(const int* __restrict__ bsum, int* __restrict__ boff){
  if (threadIdx.x==0){
    int run = 0;
    for (int b=0;b<SCB;++b){ boff[b] = run; run += bsum[b]; }
  }
}
__global__ void k_rowptr(const int* __restrict__ cnt, const int* __restrict__ boff,
                         int* __restrict__ rowptr, int* __restrict__ cursor){
  __shared__ int sh[256];
  int i = blockIdx.x*256 + threadIdx.x;
  int v = (i < NN) ? cnt[i] : 0;
  sh[threadIdx.x] = v; __syncthreads();
  #pragma unroll
  for (int o=1;o<256;o<<=1){
    int add = 0;
    if (threadIdx.x >= o) add = sh[threadIdx.x - o];
    __syncthreads();
    sh[threadIdx.x] += add;
    __syncthreads();
  }
  int excl = sh[threadIdx.x] - v + boff[blockIdx.x];
  if (i <= NN) rowptr[i] = excl;
  if (i < NN)  cursor[i] = excl;
}
__global__ void k_fill(const int* __restrict__ src, const int* __restrict__ dst,
                       const float* __restrict__ dinv, int* __restrict__ cursor,
                       int* __restrict__ ss, float* __restrict__ we){
  int e = blockIdx.x*256 + threadIdx.x;
  if (e < EE){
    int s = src[e], d = dst[e];
    int pos = atomicAdd(&cursor[d], 1);
    ss[pos] = s;
    we[pos] = dinv[s]*dinv[d];
  }
}
__global__ void k_x16(const float* __restrict__ x, half_t* __restrict__ x16){
  int idx = blockIdx.x*256 + threadIdx.x;
  if (idx < MP*KIN){
    int row = idx / KIN, k = idx - row*KIN;
    float v = (row < NN && k < 78) ? x[(size_t)row*78 + k] : 0.f;
    x16[idx] = (half_t)v;
  }
}

// ---------------- LDS-tiled coalesced transpose: src fp32 [K x 768] -> dst f16 [768 x ldk] ----------------
__global__ __launch_bounds__(256)
void k_trt(const float* __restrict__ src, half_t* __restrict__ dst,
           int K, int ldk, size_t srcStride, size_t dstStride){
  __shared__ half_t sh[32][33];
  const float* s = src + blockIdx.z*srcStride;
  half_t* d = dst + blockIdx.z*dstStride;
  const int tx = threadIdx.x & 31, ty = threadIdx.x >> 5;   // 32 x 8
  const int kb = blockIdx.y*32, nb = blockIdx.x*32;
  #pragma unroll
  for (int rloop=0; rloop<4; ++rloop){
    int krow = kb + ty*4 + rloop;
    float v = (krow < K) ? s[(size_t)krow*DD + nb + tx] : 0.f;
    sh[ty*4+rloop][tx] = (half_t)v;
  }
  __syncthreads();
  #pragma unroll
  for (int rloop=0; rloop<4; ++rloop){
    int nrow = ty*4 + rloop;
    d[(size_t)(nb + nrow)*ldk + kb + tx] = sh[tx][nrow];
  }
}

// ---------------- CSR gather, wave-per-row: 4 waves/block, lane l owns cols l+64j (j=0..11) ----------------
__global__ __launch_bounds__(256)
void k_gather(const int* __restrict__ rowptr, const int* __restrict__ ss,
              const float* __restrict__ we, const half_t* __restrict__ xw,
              const float* __restrict__ dinv, const float* __restrict__ bias,
              half_t* __restrict__ agg16, float* __restrict__ stats){
  const int t = threadIdx.x, l = t&63, wv = t>>6;
  float b_[12];
  #pragma unroll
  for (int j=0;j<12;++j) b_[j] = bias[l + 64*j];
  float s_[12], q_[12];
  #pragma unroll
  for (int j=0;j<12;++j){ s_[j]=0.f; q_[j]=0.f; }

  for (int d = blockIdx.x*4 + wv; d < NN; d += gridDim.x*4){
    int beg = rowptr[d], end = rowptr[d+1];
    float dv = dinv[d], sn = dv*dv;
    const half_t* xr = xw + (size_t)d*DD + l;
    float a_[12];
    #pragma unroll
    for (int j=0;j<12;++j) a_[j] = fmaf(sn, (float)xr[64*j], b_[j]);
    int e = beg;
    for (; e+1 < end; e += 2){
      int sA = ss[e], sB = ss[e+1];
      float wA = we[e], wB = we[e+1];
      const half_t* xA = xw + (size_t)sA*DD + l;
      const half_t* xB = xw + (size_t)sB*DD + l;
      #pragma unroll
      for (int j=0;j<12;++j) a_[j] += wA*(float)xA[64*j] + wB*(float)xB[64*j];
    }
    if (e < end){
      int sA = ss[e]; float wA = we[e];
      const half_t* xA = xw + (size_t)sA*DD + l;
      #pragma unroll
      for (int j=0;j<12;++j) a_[j] = fmaf(wA, (float)xA[64*j], a_[j]);
    }
    half_t* ar = agg16 + (size_t)d*DD + l;
    #pragma unroll
    for (int j=0;j<12;++j) ar[64*j] = (half_t)a_[j];
    #pragma unroll
    for (int j=0;j<12;++j){ s_[j]+=a_[j]; q_[j]+=a_[j]*a_[j]; }
  }

  __shared__ float red[4][24][64];   // 24 KB
  #pragma unroll
  for (int j=0;j<12;++j){ red[wv][j][l] = s_[j]; red[wv][12+j][l] = q_[j]; }
  __syncthreads();
  #pragma unroll
  for (int k=0;k<6;++k){
    int idx  = t + k*256;
    int slot = idx>>6, lane = idx&63;
    float v = red[0][slot][lane]+red[1][slot][lane]+red[2][slot][lane]+red[3][slot][lane];
    int off = (slot<12) ? (lane + 64*slot) : (DD + lane + 64*(slot-12));
    atomicAdd(&stats[off], v);
  }
}

// ---------------- fused BN-finalize + apply: h16 += relu(agg*sc + sh) ----------------
// grid MUST be 1536 blocks x 256 so each thread's column set is loop-invariant
__global__ __launch_bounds__(256)
void k_apply(const half_t* __restrict__ agg16, const float* __restrict__ stats,
             const float* __restrict__ g, const float* __restrict__ b,
             half_t* __restrict__ h16){
  const int tid = blockIdx.x*256 + threadIdx.x;
  const int col = (tid*8) % DD;
  float sc[8], sh[8];
  #pragma unroll
  for (int j=0;j<8;++j){
    float mu  = stats[col+j]    * (1.0f/NN);
    float msq = stats[DD+col+j] * (1.0f/NN);
    float var = msq - mu*mu;
    float rstd = rsqrtf(var + 1e-5f);
    float scale = rstd * g[col+j];
    sc[j] = scale;
    sh[j] = b[col+j] - mu*scale;
  }
  const int total = NN*DD/8;
  for (int i = tid; i < total; i += 1536*256){
    size_t base = (size_t)i*8;
    v8h a = *(const v8h*)(agg16 + base);
    v8h h = *(const v8h*)(h16 + base);
    v8h o;
    #pragma unroll
    for (int j=0;j<8;++j){
      float v = fmaxf(fmaf((float)a[j], sc[j], sh[j]), 0.f);
      o[j] = (half_t)((float)h[j] + v);
    }
    *(v8h*)(h16 + base) = o;
  }
}

extern "C" void kernel_launch(void* const* d_in, const int* in_sizes, int n_in,
                              void* d_out, int out_size, void* d_ws, size_t ws_size,
                              hipStream_t stream){
  (void)in_sizes; (void)n_in; (void)out_size; (void)ws_size;
  const float* x      = (const float*)d_in[0];
  const int*   ei     = (const int*)  d_in[1];
  const float* in_w   = (const float*)d_in[2];
  const float* in_b   = (const float*)d_in[3];
  const float* conv_w = (const float*)d_in[4];
  const float* conv_b = (const float*)d_in[5];
  const float* bn_g   = (const float*)d_in[6];
  const float* bn_b   = (const float*)d_in[7];
  const float* out_w  = (const float*)d_in[8];
  const float* out_b  = (const float*)d_in[9];
  float* out = (float*)d_out;
  const int* srcI = ei;
  const int* dstI = ei + EE;

  char* ws = (char*)d_ws; size_t off = 0;
  auto alloc = [&](size_t b)->void*{ void* p = ws + off; off += (b + 255) & ~(size_t)255; return p; };
  half_t* h16  = (half_t*)alloc((size_t)MP*DD*2);
  half_t* xw16 = (half_t*)alloc((size_t)MP*DD*2);
  half_t* agg16= (half_t*)alloc((size_t)NN*DD*2);
  half_t* x16  = (half_t*)alloc((size_t)MP*KIN*2);
  half_t* wT   = (half_t*)alloc((size_t)(DD*KIN + 6*DD*DD)*2);
  float* dinv   = (float*)alloc((size_t)MP*4);
  int*   cnt    = (int*)  alloc((size_t)MP*4);
  int*   rowptr = (int*)  alloc((size_t)(NN+1)*4);
  int*   cursor = (int*)  alloc((size_t)NN*4);
  int*   ssE    = (int*)  alloc((size_t)EE*4);
  float* weE    = (float*)alloc((size_t)EE*4);
  int*   bsum   = (int*)  alloc((size_t)SCB*4);
  int*   boff   = (int*)  alloc((size_t)SCB*4);
  float* stats5 = (float*)alloc((size_t)5*2*DD*4);   // 5 layers x {sum, sumsq}

  half_t* wTin = wT;
  half_t* wTc  = wT + DD*KIN;
  half_t* wTo  = wTc + 5*DD*DD;

  hipMemsetAsync(cnt, 0, (size_t)MP*4, stream);
  hipMemsetAsync(stats5, 0, (size_t)5*2*DD*4, stream);
  k_count<<<(EE+255)/256,256,0,stream>>>(dstI, cnt);
  k_dinv_bsum<<<SCB,256,0,stream>>>(cnt, dinv, bsum);
  k_btop <<<1,64,0,stream>>>(bsum, boff);
  k_rowptr<<<SCB,256,0,stream>>>(cnt, boff, rowptr, cursor);
  k_fill <<<(EE+255)/256,256,0,stream>>>(srcI, dstI, dinv, cursor, ssE, weE);
  k_x16  <<<(MP*KIN+255)/256,256,0,stream>>>(x, x16);
  {
    dim3 gin(DD/32, KIN/32, 1);            // in_w: 78x768 -> 768x96 (pad zeros)
    k_trt<<<gin,256,0,stream>>>(in_w, wTin, 78, KIN, 0, 0);
    dim3 gc(DD/32, DD/32, 5);              // conv_w: 5 x 768x768
    k_trt<<<gc,256,0,stream>>>(conv_w, wTc, DD, DD, (size_t)DD*DD, (size_t)DD*DD);
    dim3 go(DD/32, DD/32, 1);              // out_w
    k_trt<<<go,256,0,stream>>>(out_w, wTo, DD, DD, 0, 0);
  }

  const int NWG = (MP/128)*(DD/256);   // 392*3 = 1176  (divisible by 8 XCDs)
  gemm_t<0,KIN><<<NWG,256,0,stream>>>(x16, wTin, in_b, nullptr, h16);

  for (int l = 0; l < 5; ++l){
    float* statsL = stats5 + (size_t)l*2*DD;
    gemm_t<1,DD><<<NWG,256,0,stream>>>(h16, wTc + (size_t)l*DD*DD, nullptr, nullptr, xw16);
    k_gather<<<2048,256,0,stream>>>(rowptr, ssE, weE, xw16, dinv, conv_b + l*DD, agg16, statsL);
    k_apply<<<1536,256,0,stream>>>(agg16, statsL, bn_g + l*DD, bn_b + l*DD, h16);
  }

  gemm_t<2,DD><<<NWG,256,0,stream>>>(h16, wTo, out_b, out, nullptr);
}